// Round 16
// baseline (26.192 us; speedup 1.0000x reference)
//
#include <hip/hip_runtime.h>
#include <hip/hip_bf16.h>

#define SLEN 4096
#define NH 16
#define PDIM 64
#define NDIM 128
#define NBH 32   // b*h
#define KSPLIT 8
#define KB_MAIN (SLEN / KSPLIT)  // 512
#define TT 64    // t per LDS tile

typedef __attribute__((ext_vector_type(8))) short short8;
typedef __attribute__((ext_vector_type(8))) unsigned short ushort8;
typedef __attribute__((ext_vector_type(4))) float f32x4;

// raw barrier: LDS ordering via lgkmcnt only — does NOT drain vmcnt, so
// asm-issued prefetch loads stay in flight across the barrier (T4).
#define BAR()                                                                  \
    {                                                                          \
        asm volatile("s_waitcnt lgkmcnt(0)" ::: "memory");                     \
        __builtin_amdgcn_sched_barrier(0);                                     \
        __builtin_amdgcn_s_barrier();                                          \
    }

// manual vmcnt wait + rule-#18 fence (sched_barrier right after the waitcnt)
#define VMW(N)                                                                 \
    {                                                                          \
        asm volatile("s_waitcnt vmcnt(" #N ")" ::: "memory");                  \
        __builtin_amdgcn_sched_barrier(0);                                     \
    }

// opaque loads the compiler cannot sink to their uses (r11: VGPR=56 proved
// ordinary loads get sunk into CVTW -> prefetch distance was ZERO in asm)
#define GLOAD4(dst, p)                                                         \
    asm volatile("global_load_dwordx4 %0, %1, off" : "=v"(dst) : "v"(p))
#define GLOAD1(dst, p)                                                         \
    asm volatile("global_load_dword %0, %1, off" : "=v"(dst) : "v"(p))

// swizzle: spreads ds_read_b128 (rows consecutive) and transpose ds_write_b32
// (rows stride-4) across the 8 16B slots of a 128B row
__device__ __forceinline__ int swz(int r) { return ((r & 7) ^ ((r >> 2) & 7)) << 4; }

__device__ __forceinline__ unsigned short f2bfu(float x) {
    __hip_bfloat16 h = __float2bfloat16(x);
    return *reinterpret_cast<unsigned short*>(&h);
}
__device__ __forceinline__ unsigned pack2(float lo, float hi) {
    return (unsigned)f2bfu(lo) | ((unsigned)f2bfu(hi) << 16);
}

// ---------------- Fused kernel: chunk-local weights + LDS-staged GEMM ---------
// chunk_out[p,n] = sum_t exp(ls(t)) * X[t,p] * B[t,n]  (ls = in-chunk suffix);
// inter-chunk decay exp(tail) applied on accumulators in the epilogue.
// KSPLIT=8 -> 256 blocks (1/CU): minimal per-block overhead (r15: 29.4->26.1).
// r16 change: VMW hoisted ABOVE the compute phase so CVTW (VALU+ds_write, next
// buffer) and COMPUTE (ds_read+MFMA, current buffer) share one scheduling
// region -> compiler interleaves the independent phases (T3 lesson; the old
// order COMPUTE;VMW;CVTW had sched_barrier(0) blocking the interleave).
// Block: 512 thr = 8 waves (2p x 4n); wave = 32p x 32n (2x2 frags 16x16x32).
// LDS: X=[64p][64t] bf16 (8KB) + B=[128n][64t] bf16 (16KB), double-buffered.
// Real depth-2 prefetch: asm loads + counted vmcnt.
template <int KB, int NT, bool F32OUT>
__global__ __launch_bounds__(512, 4) void state_gemm_kernel(
    const float* __restrict__ X, const float* __restrict__ Bm,
    const float* __restrict__ A, void* __restrict__ partial) {
    int bh = blockIdx.x;
    int ks = blockIdx.y;
    int b = bh >> 4, h = bh & 15;
    int tid = threadIdx.x;
    int lane = tid & 63, wv_ = tid >> 6;
    int wp = wv_ & 1, wn = wv_ >> 1;
    int p0 = wp * 32, n0 = wn * 32;
    int m = lane & 15, kg = lane >> 4;
    int c = tid & 15, tp = tid >> 4;  // staging: feature-group c, t-pair tp (0..31)

    __shared__ __align__(16) char lds[2][24576];  // X at 0, B at 8192
    __shared__ float wlds[KB];
    __shared__ float sc[8];
    __shared__ float sc2[8];

    const float* Xb = X + (size_t)b * (SLEN * NH * PDIM) + h * PDIM;
    const float* Bb = Bm + (size_t)b * (SLEN * NH * NDIM) + h * NDIM;
    const float* Ab = A + (size_t)b * (SLEN * NH) + h;  // stride NH
    int t0 = ks * KB;

    const float* xsrc = Xb + (size_t)(t0 + 2 * tp) * (NH * PDIM) + 4 * c;
    const float* bsrc = Bb + (size_t)(t0 + 2 * tp) * (NH * NDIM) + 4 * c;

    // staging write byte offsets: row r=4c+i, t-col pair tp. B rows at +8192
    // (n=4c+i) and +16384 (n=4c+i+64); swz(r+64)==swz(r) so offsets share wX.
    int wX[4];
#pragma unroll
    for (int i = 0; i < 4; ++i) {
        int r = 4 * c + i;
        wX[i] = (r * 128 + 4 * tp) ^ swz(r);
    }
    // fragment read byte offsets
    int rA[2][2], rB[2][2];
#pragma unroll
    for (int pi = 0; pi < 2; ++pi)
#pragma unroll
        for (int kk = 0; kk < 2; ++kk) {
            int r = p0 + pi * 16 + m;
            rA[pi][kk] = (r * 128 + kk * 64 + kg * 16) ^ swz(r);
        }
#pragma unroll
    for (int ni = 0; ni < 2; ++ni)
#pragma unroll
        for (int kk = 0; kk < 2; ++kk) {
            int rn = n0 + ni * 16 + m;
            rB[ni][kk] = 8192 + ((rn * 128 + kk * 64 + kg * 16) ^ swz(rn));
        }

    f32x4 acc[2][2];
#pragma unroll
    for (int i = 0; i < 2; ++i)
#pragma unroll
        for (int j = 0; j < 2; ++j) acc[i][j] = (f32x4){0.f, 0.f, 0.f, 0.f};

    // two register banks for depth-2 prefetch (asm-written -> cannot be sunk)
    f32x4 rx0[2], rx1[2], rb00[2], rb01[2], rb10[2], rb11[2];

#define LOADR(it, bk)                                                          \
    {                                                                          \
        const float* xp = xsrc + (size_t)(it) * (TT * NH * PDIM);              \
        const float* bp = bsrc + (size_t)(it) * (TT * NH * NDIM);              \
        GLOAD4(rx0[bk], xp);                                                   \
        GLOAD4(rx1[bk], xp + NH * PDIM);                                       \
        GLOAD4(rb00[bk], bp);                                                  \
        GLOAD4(rb01[bk], bp + NH * NDIM);                                      \
        GLOAD4(rb10[bk], bp + 64);                                             \
        GLOAD4(rb11[bk], bp + NH * NDIM + 64);                                 \
    }

#define CVTW(buf, bk, it)                                                      \
    {                                                                          \
        float wv0 = wlds[(it) * TT + 2 * tp];                                  \
        float wv1 = wlds[(it) * TT + 2 * tp + 1];                              \
        char* dst = lds[buf];                                                  \
        _Pragma("unroll") for (int i = 0; i < 4; ++i) {                        \
            *(unsigned*)(dst + wX[i]) = pack2(rx0[bk][i] * wv0, rx1[bk][i] * wv1); \
            *(unsigned*)(dst + wX[i] + 8192) = pack2(rb00[bk][i], rb01[bk][i]);    \
            *(unsigned*)(dst + wX[i] + 16384) = pack2(rb10[bk][i], rb11[bk][i]);   \
        }                                                                      \
    }

#define COMPUTE(buf)                                                           \
    {                                                                          \
        const char* src = lds[buf];                                            \
        short8 af[2][2], bf[2][2];                                             \
        _Pragma("unroll") for (int pi = 0; pi < 2; ++pi)                       \
            _Pragma("unroll") for (int kk = 0; kk < 2; ++kk)                   \
                af[pi][kk] = *(const short8*)(src + rA[pi][kk]);               \
        _Pragma("unroll") for (int ni = 0; ni < 2; ++ni)                       \
            _Pragma("unroll") for (int kk = 0; kk < 2; ++kk)                   \
                bf[ni][kk] = *(const short8*)(src + rB[ni][kk]);               \
        _Pragma("unroll") for (int kk = 0; kk < 2; ++kk)                       \
            _Pragma("unroll") for (int pi = 0; pi < 2; ++pi)                   \
                _Pragma("unroll") for (int ni = 0; ni < 2; ++ni)               \
                    acc[pi][ni] = __builtin_amdgcn_mfma_f32_16x16x32_bf16(     \
                        af[pi][kk], bf[ni][kk], acc[pi][ni], 0, 0, 0);         \
    }

    // ---- issue order (vmcnt retires in order): la, tl, bank0, bank1 ----
    constexpr int E = (KB + 511) / 512;
    float la[E];
#pragma unroll
    for (int e = 0; e < E; ++e) {
        int idx = tid * E + e;
        int ic = idx < KB ? idx : KB - 1;  // clamp: uniform wave vmcnt counts
        GLOAD1(la[e], Ab + (size_t)(t0 + ic) * NH);
    }
    float tl[8];
#pragma unroll
    for (int i = 0; i < 8; ++i) {
        int t = t0 + KB + tid + i * 512;
        int tc = t < SLEN ? t : SLEN - 1;  // clamp; masked at consumption
        GLOAD1(tl[i], Ab + (size_t)tc * NH);
    }
    LOADR(0, 0);
    if (NT > 1) LOADR(1, 1);

    // ---- chunk-local suffix scan: wlds[i] = exp(sum_{i' > i, i' in chunk} A)
    if (F32OUT) { VMW(0); } else { VMW(20); }  // la ready; tl+banks in flight
    {
        float loc[E];
        float run = 0.f;
#pragma unroll
        for (int e = 0; e < E; ++e) {
            int idx = tid * E + e;
            run += (idx < KB) ? la[e] : 0.f;
            loc[e] = run;
        }
        float v = run;
#pragma unroll
        for (int off = 1; off < 64; off <<= 1) {
            float u = __shfl_up(v, off, 64);
            if (lane >= off) v += u;
        }
        if (lane == 63) sc[wv_] = v;  // per-wave sum
        BAR();
        float woff = 0.f, tot = 0.f;
#pragma unroll
        for (int q = 0; q < 8; ++q) {
            float s_ = sc[q];
            tot += s_;
            if (q < wv_) woff += s_;
        }
        float excl = woff + v - run;
#pragma unroll
        for (int e = 0; e < E; ++e) {
            int idx = tid * E + e;
            if (idx < KB) wlds[idx] = expf(tot - (excl + loc[e]));
        }
        BAR();
    }

    if (F32OUT) { VMW(0); } else { VMW(6); }  // bank0 ready; bank1 in flight
    CVTW(0, 0, 0);
    BAR();

#pragma unroll
    for (int it = 0; it < NT; ++it) {
        if (it + 2 < NT) LOADR(it + 2, it & 1);  // issue 2 tiles ahead (asm)
        if (it + 1 < NT) {
            // wait for bank(it+1) BEFORE the compute region so CVTW and
            // COMPUTE share one scheduling region (interleaved by compiler)
            if (!F32OUT && it + 2 < NT) { VMW(6); }  // bank(it+1) ready
            else { VMW(0); }                          // tail: drain
            COMPUTE(it & 1);                          // ds_read+MFMA, buf it&1
            CVTW((it + 1) & 1, (it + 1) & 1, it + 1); // VALU+ds_write, other buf
        } else {
            COMPUTE(it & 1);
        }
        BAR();  // lgkm-only: outstanding prefetch survives the barrier
    }
#undef LOADR
#undef CVTW
#undef COMPUTE

    // ---- epilogue: tail sum (tl retired by the vmcnt chain) -> scale ----
    float ts = 0.f;
#pragma unroll
    for (int i = 0; i < 8; ++i) {
        int t = t0 + KB + tid + i * 512;
        ts += (t < SLEN) ? tl[i] : 0.f;
    }
#pragma unroll
    for (int off = 32; off > 0; off >>= 1) ts += __shfl_xor(ts, off, 64);
    if (lane == 0) sc2[wv_] = ts;
    BAR();
    float tsum = 0.f;
#pragma unroll
    for (int q = 0; q < 8; ++q) tsum += sc2[q];
    float scale = expf(tsum);

    if (F32OUT) {
        float* outp = (float*)partial + (size_t)bh * (PDIM * NDIM);
#pragma unroll
        for (int pi = 0; pi < 2; ++pi)
#pragma unroll
            for (int ni = 0; ni < 2; ++ni)
#pragma unroll
                for (int r = 0; r < 4; ++r) {
                    int p = p0 + pi * 16 + kg * 4 + r;  // C/D: row=(lane>>4)*4+reg
                    int n = n0 + ni * 16 + m;           // C/D: col=lane&15
                    outp[p * NDIM + n] = acc[pi][ni][r] * scale;
                }
    } else {
        __hip_bfloat16* outp =
            (__hip_bfloat16*)partial + ((size_t)ks * NBH + bh) * (PDIM * NDIM);
#pragma unroll
        for (int pi = 0; pi < 2; ++pi)
#pragma unroll
            for (int ni = 0; ni < 2; ++ni)
#pragma unroll
                for (int r = 0; r < 4; ++r) {
                    int p = p0 + pi * 16 + kg * 4 + r;
                    int n = n0 + ni * 16 + m;
                    outp[p * NDIM + n] = __float2bfloat16(acc[pi][ni][r] * scale);
                }
    }
}

// ---------------- Kernel 2: reduce K-split bf16 partials -----------------------
__global__ void reduce_kernel(const __hip_bfloat16* __restrict__ partial,
                              float* __restrict__ out, int ksplit) {
    int i = blockIdx.x * 256 + threadIdx.x;  // 8-output group index
    float s[8];
#pragma unroll
    for (int j = 0; j < 8; ++j) s[j] = 0.f;
    for (int ks = 0; ks < ksplit; ++ks) {
        ushort8 v = *(const ushort8*)((const unsigned short*)partial +
                                      (size_t)ks * (NBH * PDIM * NDIM) + (size_t)i * 8);
#pragma unroll
        for (int j = 0; j < 8; ++j) {
            unsigned u = ((unsigned)v[j]) << 16;
            s[j] += *reinterpret_cast<float*>(&u);
        }
    }
    *(f32x4*)(out + (size_t)i * 8) = (f32x4){s[0], s[1], s[2], s[3]};
    *(f32x4*)(out + (size_t)i * 8 + 4) = (f32x4){s[4], s[5], s[6], s[7]};
}

extern "C" void kernel_launch(void* const* d_in, const int* in_sizes, int n_in,
                              void* d_out, int out_size, void* d_ws, size_t ws_size,
                              hipStream_t stream) {
    const float* X = (const float*)d_in[0];
    const float* A = (const float*)d_in[1];
    const float* Bm = (const float*)d_in[2];
    // d_in[3] (C) is unused by the reference.
    float* out = (float*)d_out;

    __hip_bfloat16* partial = (__hip_bfloat16*)d_ws;
    size_t pbytes = (size_t)KSPLIT * NBH * PDIM * NDIM * sizeof(__hip_bfloat16);

    if (ws_size < pbytes) {
        // degenerate fallback: whole sequence per block, f32 straight into out
        state_gemm_kernel<SLEN, SLEN / TT, true>
            <<<dim3(NBH, 1), 512, 0, stream>>>(X, Bm, A, out);
        return;
    }
    state_gemm_kernel<KB_MAIN, KB_MAIN / TT, false>
        <<<dim3(NBH, KSPLIT), 512, 0, stream>>>(X, Bm, A, partial);
    int ngrp = NBH * PDIM * NDIM / 8;  // 8 outputs per thread
    reduce_kernel<<<ngrp / 256, 256, 0, stream>>>(partial, out, KSPLIT);
}

// Round 17
// 26.034 us; speedup vs baseline: 1.0061x; 1.0061x over previous
//
#include <hip/hip_runtime.h>
#include <hip/hip_bf16.h>

#define SLEN 4096
#define NH 16
#define PDIM 64
#define NDIM 128
#define NBH 32   // b*h
#define KSPLIT 8
#define KB_MAIN (SLEN / KSPLIT)  // 512
#define TT 64    // t per LDS tile

typedef __attribute__((ext_vector_type(8))) short short8;
typedef __attribute__((ext_vector_type(8))) unsigned short ushort8;
typedef __attribute__((ext_vector_type(4))) float f32x4;

// raw barrier: LDS ordering via lgkmcnt only — does NOT drain vmcnt, so
// asm-issued prefetch loads stay in flight across the barrier (T4).
#define BAR()                                                                  \
    {                                                                          \
        asm volatile("s_waitcnt lgkmcnt(0)" ::: "memory");                     \
        __builtin_amdgcn_sched_barrier(0);                                     \
        __builtin_amdgcn_s_barrier();                                          \
    }

// manual vmcnt wait + rule-#18 fence (sched_barrier right after the waitcnt)
#define VMW(N)                                                                 \
    {                                                                          \
        asm volatile("s_waitcnt vmcnt(" #N ")" ::: "memory");                  \
        __builtin_amdgcn_sched_barrier(0);                                     \
    }

// opaque loads the compiler cannot sink to their uses (r11: VGPR=56 proved
// ordinary loads get sunk into CVTW -> prefetch distance was ZERO in asm)
#define GLOAD4(dst, p)                                                         \
    asm volatile("global_load_dwordx4 %0, %1, off" : "=v"(dst) : "v"(p))
#define GLOAD1(dst, p)                                                         \
    asm volatile("global_load_dword %0, %1, off" : "=v"(dst) : "v"(p))

// swizzle: spreads ds_read_b128 (rows consecutive) and transpose ds_write_b32
// (rows stride-4) across the 8 16B slots of a 128B row
__device__ __forceinline__ int swz(int r) { return ((r & 7) ^ ((r >> 2) & 7)) << 4; }

__device__ __forceinline__ unsigned short f2bfu(float x) {
    __hip_bfloat16 h = __float2bfloat16(x);
    return *reinterpret_cast<unsigned short*>(&h);
}
__device__ __forceinline__ unsigned pack2(float lo, float hi) {
    return (unsigned)f2bfu(lo) | ((unsigned)f2bfu(hi) << 16);
}

// ---------------- Fused kernel: chunk-local weights + LDS-staged GEMM ---------
// chunk_out[p,n] = sum_t exp(ls(t)) * X[t,p] * B[t,n]  (ls = in-chunk suffix);
// inter-chunk decay exp(tail) applied on accumulators in the epilogue.
// r17 fix: issue order la, bank0, bank1, tl (tail loads LAST). The old order
// (la, tl, banks) made the first CVTW's vmcnt retire all 8 scattered tail-
// gather insts (~4096 cachelines, epilogue-only data) before staging tile 0 —
// fully exposed serial time at 1 block/CU. Ledger: scan=vmcnt(20) [la ready],
// CVTW0 & loop-it0 = vmcnt(14) [bank ready, tl+next in flight], it>=1 =
// vmcnt(6) [tl older than bank(it+2), retires free], tails vmcnt(0).
// Block: 512 thr = 8 waves (2p x 4n); wave = 32p x 32n (2x2 frags 16x16x32).
// LDS: X=[64p][64t] bf16 (8KB) + B=[128n][64t] bf16 (16KB), double-buffered.
template <int KB, int NT, bool F32OUT>
__global__ __launch_bounds__(512, 4) void state_gemm_kernel(
    const float* __restrict__ X, const float* __restrict__ Bm,
    const float* __restrict__ A, void* __restrict__ partial) {
    int bh = blockIdx.x;
    int ks = blockIdx.y;
    int b = bh >> 4, h = bh & 15;
    int tid = threadIdx.x;
    int lane = tid & 63, wv_ = tid >> 6;
    int wp = wv_ & 1, wn = wv_ >> 1;
    int p0 = wp * 32, n0 = wn * 32;
    int m = lane & 15, kg = lane >> 4;
    int c = tid & 15, tp = tid >> 4;  // staging: feature-group c, t-pair tp (0..31)

    __shared__ __align__(16) char lds[2][24576];  // X at 0, B at 8192
    __shared__ float wlds[KB];
    __shared__ float sc[8];
    __shared__ float sc2[8];

    const float* Xb = X + (size_t)b * (SLEN * NH * PDIM) + h * PDIM;
    const float* Bb = Bm + (size_t)b * (SLEN * NH * NDIM) + h * NDIM;
    const float* Ab = A + (size_t)b * (SLEN * NH) + h;  // stride NH
    int t0 = ks * KB;

    const float* xsrc = Xb + (size_t)(t0 + 2 * tp) * (NH * PDIM) + 4 * c;
    const float* bsrc = Bb + (size_t)(t0 + 2 * tp) * (NH * NDIM) + 4 * c;

    // staging write byte offsets: row r=4c+i, t-col pair tp. B rows at +8192
    // (n=4c+i) and +16384 (n=4c+i+64); swz(r+64)==swz(r) so offsets share wX.
    int wX[4];
#pragma unroll
    for (int i = 0; i < 4; ++i) {
        int r = 4 * c + i;
        wX[i] = (r * 128 + 4 * tp) ^ swz(r);
    }
    // fragment read byte offsets
    int rA[2][2], rB[2][2];
#pragma unroll
    for (int pi = 0; pi < 2; ++pi)
#pragma unroll
        for (int kk = 0; kk < 2; ++kk) {
            int r = p0 + pi * 16 + m;
            rA[pi][kk] = (r * 128 + kk * 64 + kg * 16) ^ swz(r);
        }
#pragma unroll
    for (int ni = 0; ni < 2; ++ni)
#pragma unroll
        for (int kk = 0; kk < 2; ++kk) {
            int rn = n0 + ni * 16 + m;
            rB[ni][kk] = 8192 + ((rn * 128 + kk * 64 + kg * 16) ^ swz(rn));
        }

    f32x4 acc[2][2];
#pragma unroll
    for (int i = 0; i < 2; ++i)
#pragma unroll
        for (int j = 0; j < 2; ++j) acc[i][j] = (f32x4){0.f, 0.f, 0.f, 0.f};

    // two register banks for depth-2 prefetch (asm-written -> cannot be sunk)
    f32x4 rx0[2], rx1[2], rb00[2], rb01[2], rb10[2], rb11[2];

#define LOADR(it, bk)                                                          \
    {                                                                          \
        const float* xp = xsrc + (size_t)(it) * (TT * NH * PDIM);              \
        const float* bp = bsrc + (size_t)(it) * (TT * NH * NDIM);              \
        GLOAD4(rx0[bk], xp);                                                   \
        GLOAD4(rx1[bk], xp + NH * PDIM);                                       \
        GLOAD4(rb00[bk], bp);                                                  \
        GLOAD4(rb01[bk], bp + NH * NDIM);                                      \
        GLOAD4(rb10[bk], bp + 64);                                             \
        GLOAD4(rb11[bk], bp + NH * NDIM + 64);                                 \
    }

#define CVTW(buf, bk, it)                                                      \
    {                                                                          \
        float wv0 = wlds[(it) * TT + 2 * tp];                                  \
        float wv1 = wlds[(it) * TT + 2 * tp + 1];                              \
        char* dst = lds[buf];                                                  \
        _Pragma("unroll") for (int i = 0; i < 4; ++i) {                        \
            *(unsigned*)(dst + wX[i]) = pack2(rx0[bk][i] * wv0, rx1[bk][i] * wv1); \
            *(unsigned*)(dst + wX[i] + 8192) = pack2(rb00[bk][i], rb01[bk][i]);    \
            *(unsigned*)(dst + wX[i] + 16384) = pack2(rb10[bk][i], rb11[bk][i]);   \
        }                                                                      \
    }

#define COMPUTE(buf)                                                           \
    {                                                                          \
        const char* src = lds[buf];                                            \
        short8 af[2][2], bf[2][2];                                             \
        _Pragma("unroll") for (int pi = 0; pi < 2; ++pi)                       \
            _Pragma("unroll") for (int kk = 0; kk < 2; ++kk)                   \
                af[pi][kk] = *(const short8*)(src + rA[pi][kk]);               \
        _Pragma("unroll") for (int ni = 0; ni < 2; ++ni)                       \
            _Pragma("unroll") for (int kk = 0; kk < 2; ++kk)                   \
                bf[ni][kk] = *(const short8*)(src + rB[ni][kk]);               \
        _Pragma("unroll") for (int kk = 0; kk < 2; ++kk)                       \
            _Pragma("unroll") for (int pi = 0; pi < 2; ++pi)                   \
                _Pragma("unroll") for (int ni = 0; ni < 2; ++ni)               \
                    acc[pi][ni] = __builtin_amdgcn_mfma_f32_16x16x32_bf16(     \
                        af[pi][kk], bf[ni][kk], acc[pi][ni], 0, 0, 0);         \
    }

    // ---- issue order (vmcnt retires in order): la, bank0, bank1, tl ----
    constexpr int E = (KB + 511) / 512;
    float la[E];
#pragma unroll
    for (int e = 0; e < E; ++e) {
        int idx = tid * E + e;
        int ic = idx < KB ? idx : KB - 1;  // clamp: uniform wave vmcnt counts
        GLOAD1(la[e], Ab + (size_t)(t0 + ic) * NH);
    }
    LOADR(0, 0);
    if (NT > 1) LOADR(1, 1);
    // tail loads LAST: consumed only in the epilogue, must not gate staging
    float tl[8];
#pragma unroll
    for (int i = 0; i < 8; ++i) {
        int t = t0 + KB + tid + i * 512;
        int tc = t < SLEN ? t : SLEN - 1;  // clamp; masked at consumption
        GLOAD1(tl[i], Ab + (size_t)tc * NH);
    }

    // ---- chunk-local suffix scan: wlds[i] = exp(sum_{i' > i, i' in chunk} A)
    if (F32OUT) { VMW(0); } else { VMW(20); }  // la ready; banks+tl in flight
    {
        float loc[E];
        float run = 0.f;
#pragma unroll
        for (int e = 0; e < E; ++e) {
            int idx = tid * E + e;
            run += (idx < KB) ? la[e] : 0.f;
            loc[e] = run;
        }
        float v = run;
#pragma unroll
        for (int off = 1; off < 64; off <<= 1) {
            float u = __shfl_up(v, off, 64);
            if (lane >= off) v += u;
        }
        if (lane == 63) sc[wv_] = v;  // per-wave sum
        BAR();
        float woff = 0.f, tot = 0.f;
#pragma unroll
        for (int q = 0; q < 8; ++q) {
            float s_ = sc[q];
            tot += s_;
            if (q < wv_) woff += s_;
        }
        float excl = woff + v - run;
#pragma unroll
        for (int e = 0; e < E; ++e) {
            int idx = tid * E + e;
            if (idx < KB) wlds[idx] = expf(tot - (excl + loc[e]));
        }
        BAR();
    }

    // bank0 ready; bank1(6)+tl(8) stay in flight
    if (F32OUT) { VMW(0); } else { VMW(14); }
    CVTW(0, 0, 0);
    BAR();

#pragma unroll
    for (int it = 0; it < NT; ++it) {
        if (it + 2 < NT) LOADR(it + 2, it & 1);  // issue 2 tiles ahead (asm)
        if (it + 1 < NT) {
            // gate on bank(it+1) only; tl retires with (older than) bank(it+2)
            if (F32OUT) { VMW(0); }
            else if (it == 0 && 2 < NT) { VMW(14); }   // tl(8)+bank2(6) in flight
            else if (it + 2 < NT) { VMW(6); }          // bank(it+2) in flight
            else { VMW(0); }                            // tail: drain all
            COMPUTE(it & 1);                            // ds_read+MFMA, buf it&1
            CVTW((it + 1) & 1, (it + 1) & 1, it + 1);   // VALU+ds_write, other buf
        } else {
            COMPUTE(it & 1);
        }
        BAR();  // lgkm-only: outstanding prefetch survives the barrier
    }
#undef LOADR
#undef CVTW
#undef COMPUTE

    // ---- epilogue: tail sum (tl drained by the final vmcnt(0)) -> scale ----
    float ts = 0.f;
#pragma unroll
    for (int i = 0; i < 8; ++i) {
        int t = t0 + KB + tid + i * 512;
        ts += (t < SLEN) ? tl[i] : 0.f;
    }
#pragma unroll
    for (int off = 32; off > 0; off >>= 1) ts += __shfl_xor(ts, off, 64);
    if (lane == 0) sc2[wv_] = ts;
    BAR();
    float tsum = 0.f;
#pragma unroll
    for (int q = 0; q < 8; ++q) tsum += sc2[q];
    float scale = expf(tsum);

    if (F32OUT) {
        float* outp = (float*)partial + (size_t)bh * (PDIM * NDIM);
#pragma unroll
        for (int pi = 0; pi < 2; ++pi)
#pragma unroll
            for (int ni = 0; ni < 2; ++ni)
#pragma unroll
                for (int r = 0; r < 4; ++r) {
                    int p = p0 + pi * 16 + kg * 4 + r;  // C/D: row=(lane>>4)*4+reg
                    int n = n0 + ni * 16 + m;           // C/D: col=lane&15
                    outp[p * NDIM + n] = acc[pi][ni][r] * scale;
                }
    } else {
        __hip_bfloat16* outp =
            (__hip_bfloat16*)partial + ((size_t)ks * NBH + bh) * (PDIM * NDIM);
#pragma unroll
        for (int pi = 0; pi < 2; ++pi)
#pragma unroll
            for (int ni = 0; ni < 2; ++ni)
#pragma unroll
                for (int r = 0; r < 4; ++r) {
                    int p = p0 + pi * 16 + kg * 4 + r;
                    int n = n0 + ni * 16 + m;
                    outp[p * NDIM + n] = __float2bfloat16(acc[pi][ni][r] * scale);
                }
    }
}

// ---------------- Kernel 2: reduce K-split bf16 partials -----------------------
__global__ void reduce_kernel(const __hip_bfloat16* __restrict__ partial,
                              float* __restrict__ out, int ksplit) {
    int i = blockIdx.x * 256 + threadIdx.x;  // 8-output group index
    float s[8];
#pragma unroll
    for (int j = 0; j < 8; ++j) s[j] = 0.f;
    for (int ks = 0; ks < ksplit; ++ks) {
        ushort8 v = *(const ushort8*)((const unsigned short*)partial +
                                      (size_t)ks * (NBH * PDIM * NDIM) + (size_t)i * 8);
#pragma unroll
        for (int j = 0; j < 8; ++j) {
            unsigned u = ((unsigned)v[j]) << 16;
            s[j] += *reinterpret_cast<float*>(&u);
        }
    }
    *(f32x4*)(out + (size_t)i * 8) = (f32x4){s[0], s[1], s[2], s[3]};
    *(f32x4*)(out + (size_t)i * 8 + 4) = (f32x4){s[4], s[5], s[6], s[7]};
}

extern "C" void kernel_launch(void* const* d_in, const int* in_sizes, int n_in,
                              void* d_out, int out_size, void* d_ws, size_t ws_size,
                              hipStream_t stream) {
    const float* X = (const float*)d_in[0];
    const float* A = (const float*)d_in[1];
    const float* Bm = (const float*)d_in[2];
    // d_in[3] (C) is unused by the reference.
    float* out = (float*)d_out;

    __hip_bfloat16* partial = (__hip_bfloat16*)d_ws;
    size_t pbytes = (size_t)KSPLIT * NBH * PDIM * NDIM * sizeof(__hip_bfloat16);

    if (ws_size < pbytes) {
        // degenerate fallback: whole sequence per block, f32 straight into out
        state_gemm_kernel<SLEN, SLEN / TT, true>
            <<<dim3(NBH, 1), 512, 0, stream>>>(X, Bm, A, out);
        return;
    }
    state_gemm_kernel<KB_MAIN, KB_MAIN / TT, false>
        <<<dim3(NBH, KSPLIT), 512, 0, stream>>>(X, Bm, A, partial);
    int ngrp = NBH * PDIM * NDIM / 8;  // 8 outputs per thread
    reduce_kernel<<<ngrp / 256, 256, 0, stream>>>(partial, out, KSPLIT);
}